// Round 4
// baseline (8486.953 us; speedup 1.0000x reference)
//
#include <hip/hip_runtime.h>

// Generator_78683800862785: attention+LSTM decoder, BS=1024, T=30.
// R4: single persistent kernel for the whole 30-step decode; phases separated
// by device-scope grid barriers (256 blocks = 1/CU, co-resident). fp16 MFMA,
// fp32 accum; K/V folded into C = scale*K_w^T Q_w; att->out->fc1 folded into
// Wfc1; LSTM gate-ew fused after GEMM (weight rows h*4+gate).

#define DEVI __device__ __forceinline__

typedef _Float16 f16x8 __attribute__((ext_vector_type(8)));
typedef _Float16 f16x4 __attribute__((ext_vector_type(4)));
typedef _Float16 f16x2 __attribute__((ext_vector_type(2)));
typedef float    f32x4 __attribute__((ext_vector_type(4)));

#define BSZ 1024
#define SEQ 100
#define ENC 256
#define LAT 64
#define TT  30

#define MFMA16(a, b, c) __builtin_amdgcn_mfma_f32_16x16x32_f16(a, b, c, 0, 0, 0)

DEVI float lrelu(float v) { return v >= 0.f ? v : 0.2f * v; }
DEVI float sigm(float x)  { return 1.f / (1.f + __expf(-x)); }
DEVI float tanh_f(float x){ return 1.f - 2.f / (1.f + __expf(2.f * x)); }

// ---------------------------------------------------------------- setup kernels
__global__ __launch_bounds__(256) void zero_ws(uint4* __restrict__ p) {
    uint4 z; z.x = z.y = z.z = z.w = 0u;
    p[(size_t)blockIdx.x * 256 + threadIdx.x] = z;
}

__global__ __launch_bounds__(256) void conv_enc(const float4* __restrict__ src,
                                                f16x4* __restrict__ dst) {
    size_t i = (size_t)blockIdx.x * 256 + threadIdx.x;
    float4 v = src[i];
    f16x4 h;
    h.x = (_Float16)v.x; h.y = (_Float16)v.y; h.z = (_Float16)v.z; h.w = (_Float16)v.w;
    dst[i] = h;
}

// C[ne,h] = scale * sum_d k_w[n*128+d, e] * q_w[n*128+d, h]   (fp16 out)
// d[ne]   = scale * sum_d k_w[n*128+d, e] * q_b[n*128+d]
__global__ __launch_bounds__(256) void prep_qk(const float* __restrict__ k_w,
                                               const float* __restrict__ q_w,
                                               const float* __restrict__ q_b,
                                               _Float16* __restrict__ C_h,
                                               float* __restrict__ d_f,
                                               _Float16* __restrict__ d_h) {
    const int ne = blockIdx.x, n = ne >> 8, e = ne & 255, tid = threadIdx.x;
    const float scale = 0.08838834764831845f;  // 1/sqrt(128)
    float a0 = 0.f, a1 = 0.f;
    for (int dd = 0; dd < 128; ++dd) {
        float kv = k_w[(n * 128 + dd) * 256 + e];
        a0 += kv * q_w[(n * 128 + dd) * 512 + tid];
        a1 += kv * q_w[(n * 128 + dd) * 512 + 256 + tid];
    }
    C_h[(size_t)ne * 512 + tid]       = (_Float16)(scale * a0);
    C_h[(size_t)ne * 512 + 256 + tid] = (_Float16)(scale * a1);
    float pq = (tid < 128) ? k_w[(n * 128 + tid) * 256 + e] * q_b[n * 128 + tid] : 0.f;
    #pragma unroll
    for (int off = 32; off; off >>= 1) pq += __shfl_down(pq, off);
    __shared__ float red[4];
    if ((tid & 63) == 0) red[tid >> 6] = pq;
    __syncthreads();
    if (tid == 0) {
        float s = scale * (red[0] + red[1] + red[2] + red[3]);
        d_f[ne] = s; d_h[ne] = (_Float16)s;
    }
}

// A[h,k] = sum_m fc1_w[h, m] * out_w[m, k]
__global__ __launch_bounds__(256) void prep_A(const float* __restrict__ fc1_w,
                                              const float* __restrict__ out_w,
                                              float* __restrict__ A) {
    const int h = blockIdx.x, tid = threadIdx.x;
    float a0 = 0.f, a1 = 0.f;
    for (int m = 0; m < 512; ++m) {
        float fv = fc1_w[h * 576 + m];
        a0 += fv * out_w[m * 512 + tid];
        a1 += fv * out_w[m * 512 + 256 + tid];
    }
    A[(size_t)h * 512 + tid]       = a0;
    A[(size_t)h * 512 + 256 + tid] = a1;
}

// Wfc1[h, n*256+e] = sum_d A[h, n*128+d]*v_w[n*128+d, e]; cols 1024..1087 = fc1_w[h,512+l]
__global__ __launch_bounds__(256) void prep_wfc1(const float* __restrict__ A,
                                                 const float* __restrict__ v_w,
                                                 const float* __restrict__ v_b,
                                                 const float* __restrict__ fc1_w,
                                                 const float* __restrict__ out_b,
                                                 const float* __restrict__ fc1_b,
                                                 _Float16* __restrict__ Wfc1,
                                                 float* __restrict__ biasf) {
    const int h = blockIdx.x, tid = threadIdx.x;
    #pragma unroll
    for (int g = 0; g < 4; ++g) {
        float acc = 0.f;
        for (int dd = 0; dd < 128; ++dd)
            acc += A[h * 512 + g * 128 + dd] * v_w[(g * 128 + dd) * 256 + tid];
        Wfc1[(size_t)h * 1088 + g * 256 + tid] = (_Float16)acc;
    }
    if (tid < 64)
        Wfc1[(size_t)h * 1088 + 1024 + tid] = (_Float16)fc1_w[h * 576 + 512 + tid];
    float ps = A[h * 512 + tid] * v_b[tid] + A[h * 512 + 256 + tid] * v_b[256 + tid]
             + fc1_w[h * 576 + tid] * out_b[tid] + fc1_w[h * 576 + 256 + tid] * out_b[256 + tid];
    #pragma unroll
    for (int off = 32; off; off >>= 1) ps += __shfl_down(ps, off);
    __shared__ float red[4];
    if ((tid & 63) == 0) red[tid >> 6] = ps;
    __syncthreads();
    if (tid == 0) biasf[h] = red[0] + red[1] + red[2] + red[3] + fc1_b[h];
}

// LSTM weights: concat [wih|whh] -> fp16 [2048 x 1024], rows reordered to h*4+gate.
__global__ __launch_bounds__(256) void prep_lstm(const float* __restrict__ wih,
                                                 const float* __restrict__ whh,
                                                 const float* __restrict__ bih,
                                                 const float* __restrict__ bhh,
                                                 _Float16* __restrict__ Wc,
                                                 float* __restrict__ bc) {
    int idx = blockIdx.x * 256 + threadIdx.x;  // 2,097,152
    int rp = idx >> 10, cc = idx & 1023;
    int h = rp >> 2, g = rp & 3;
    int rsrc = g * 512 + h;
    float v = (cc < 512) ? wih[(size_t)rsrc * 512 + cc] : whh[(size_t)rsrc * 512 + cc - 512];
    Wc[idx] = (_Float16)v;
    if (idx < 2048) {
        int h2 = idx >> 2, g2 = idx & 3;
        bc[idx] = bih[g2 * 512 + h2] + bhh[g2 * 512 + h2];
    }
}

// fc2 weights -> fp16 casts (GEMMs run X @ W^T, so no transpose needed).
__global__ __launch_bounds__(256) void prep_fc2c(const float* __restrict__ aw,
                                                 const float* __restrict__ bw,
                                                 const float* __restrict__ cw,
                                                 _Float16* __restrict__ a16,
                                                 _Float16* __restrict__ b16,
                                                 _Float16* __restrict__ c16) {
    int i = blockIdx.x * 256 + threadIdx.x;
    if (i < 131072) a16[i] = (_Float16)aw[i];
    else if (i < 163840) b16[i - 131072] = (_Float16)bw[i - 131072];
    else if (i < 164096) c16[i - 163840] = (_Float16)cw[i - 163840];
}

__global__ __launch_bounds__(256) void bcast_G(const _Float16* __restrict__ d_h,
                                               _Float16* __restrict__ G) {
    const int b = blockIdx.x, tid = threadIdx.x;
    f16x4 v = *(const f16x4*)(d_h + tid * 4);
    *(f16x4*)(G + (size_t)b * 1024 + tid * 4) = v;
}

// ---------------------------------------------------------------- grid barrier
// Sense-reversing, device(agent)-scope. All 256 blocks co-resident (1/CU).
DEVI void gbar(unsigned* bar) {
    __syncthreads();
    if (threadIdx.x == 0) {
        unsigned g = __hip_atomic_load(bar + 1, __ATOMIC_RELAXED, __HIP_MEMORY_SCOPE_AGENT);
        unsigned a = __hip_atomic_fetch_add(bar, 1u, __ATOMIC_ACQ_REL, __HIP_MEMORY_SCOPE_AGENT);
        if (a == 255u) {
            __hip_atomic_store(bar, 0u, __ATOMIC_RELAXED, __HIP_MEMORY_SCOPE_AGENT);
            __hip_atomic_store(bar + 1, g + 1u, __ATOMIC_RELEASE, __HIP_MEMORY_SCOPE_AGENT);
        } else {
            while (__hip_atomic_load(bar + 1, __ATOMIC_ACQUIRE, __HIP_MEMORY_SCOPE_AGENT) == g)
                __builtin_amdgcn_s_sleep(1);
        }
    }
    __syncthreads();
}

// ---------------------------------------------------------------- GEMM core (512 thr, reg-db)
// out = X @ W^T on BMxBN tile; W row-major [N,K]. acc: row=(lane>>4)*4+r, col=lane&15.
template <int BM, int BN, int BK, int WM, int WN>
DEVI void pgemm(char* smem_raw, const _Float16* __restrict__ X, int ldx,
                const _Float16* __restrict__ W, int ldw, int K,
                int bm0, int bn0, f32x4* acc) {
    constexpr int LDT = BK + 8;
    _Float16* Xs = (_Float16*)smem_raw;
    _Float16* Ws = Xs + BM * LDT;
    const int tid = threadIdx.x, wave = tid >> 6, lane = tid & 63;
    constexpr int WROWS = BM / WM;
    const int wm = wave % WROWS, wn = wave / WROWS;
    constexpr int MT = WM / 16, NT = WN / 16;
    const int q = lane >> 4, m15 = lane & 15;
    constexpr int CPR = BK / 8;
    constexpr int XCH = BM * CPR, WCH = BN * CPR;
    constexpr int XPT = (XCH + 511) / 512, WPT = (WCH + 511) / 512;
    uint4 xr[XPT], wr[WPT];
    auto ldregs = [&](int k0) {
        #pragma unroll
        for (int c = 0; c < XPT; ++c) {
            int cc = tid + c * 512;
            if ((XCH % 512 == 0) || cc < XCH) {
                int row = cc / CPR, col = (cc % CPR) * 8;
                xr[c] = *(const uint4*)&X[(size_t)(bm0 + row) * ldx + k0 + col];
            }
        }
        #pragma unroll
        for (int c = 0; c < WPT; ++c) {
            int cc = tid + c * 512;
            if ((WCH % 512 == 0) || cc < WCH) {
                int row = cc / CPR, col = (cc % CPR) * 8;
                wr[c] = *(const uint4*)&W[(size_t)(bn0 + row) * ldw + k0 + col];
            }
        }
    };
    ldregs(0);
    for (int k0 = 0; k0 < K; k0 += BK) {
        #pragma unroll
        for (int c = 0; c < XPT; ++c) {
            int cc = tid + c * 512;
            if ((XCH % 512 == 0) || cc < XCH) {
                int row = cc / CPR, col = (cc % CPR) * 8;
                *(uint4*)&Xs[row * LDT + col] = xr[c];
            }
        }
        #pragma unroll
        for (int c = 0; c < WPT; ++c) {
            int cc = tid + c * 512;
            if ((WCH % 512 == 0) || cc < WCH) {
                int row = cc / CPR, col = (cc % CPR) * 8;
                *(uint4*)&Ws[row * LDT + col] = wr[c];
            }
        }
        __syncthreads();
        if (k0 + BK < K) ldregs(k0 + BK);   // overlap next-tile loads with MFMA
        #pragma unroll
        for (int kk = 0; kk < BK / 32; ++kk) {
            f16x8 af[MT], bf[NT];
            #pragma unroll
            for (int i = 0; i < MT; ++i)
                af[i] = *(const f16x8*)&Xs[(wm * WM + i * 16 + m15) * LDT + kk * 32 + q * 8];
            #pragma unroll
            for (int j = 0; j < NT; ++j)
                bf[j] = *(const f16x8*)&Ws[(wn * WN + j * 16 + m15) * LDT + kk * 32 + q * 8];
            #pragma unroll
            for (int i = 0; i < MT; ++i)
                #pragma unroll
                for (int j = 0; j < NT; ++j)
                    acc[i * NT + j] = MFMA16(af[i], bf[j], acc[i * NT + j]);
        }
        __syncthreads();
    }
}

template <int BM, int BN, int WM, int WN, int ACT>
DEVI void epi_plain(const f32x4* acc, const float* __restrict__ bias,
                    _Float16* __restrict__ out, int ldo, int bm0, int bn0) {
    const int tid = threadIdx.x, wave = tid >> 6, lane = tid & 63;
    constexpr int WROWS = BM / WM;
    const int wm = wave % WROWS, wn = wave / WROWS;
    constexpr int MT = WM / 16, NT = WN / 16;
    const int q = lane >> 4, m15 = lane & 15;
    #pragma unroll
    for (int i = 0; i < MT; ++i) {
        #pragma unroll
        for (int j = 0; j < NT; ++j) {
            int col = bn0 + wn * WN + j * 16 + m15;
            float bv = bias[col];
            #pragma unroll
            for (int r = 0; r < 4; ++r) {
                int rowg = bm0 + wm * WM + i * 16 + q * 4 + r;
                float v = acc[i * NT + j][r] + bv;
                if (ACT == 1) v = lrelu(v);
                out[(size_t)rowg * ldo + col] = (_Float16)v;
            }
        }
    }
}

// LSTM epilogue: bias + gate math fused; weight rows h*4+gate so each 128-col
// tile owns 32 h x 4 gates. acc from pgemm<64,128,64,32,32>.
DEVI void lstm_epi(char* smem, const f32x4* acc, const float* __restrict__ bias,
                   float* __restrict__ cvec, _Float16* __restrict__ h0,
                   _Float16* __restrict__ h1, int bm0, int bn0, bool copy) {
    float* accs = (float*)smem;  // [64][132]
    const int tid = threadIdx.x, wave = tid >> 6, lane = tid & 63;
    const int wm = wave & 1, wn = wave >> 1, q = lane >> 4, m15 = lane & 15;
    #pragma unroll
    for (int i = 0; i < 2; ++i) {
        #pragma unroll
        for (int j = 0; j < 2; ++j) {
            int cl = wn * 32 + j * 16 + m15;
            float bv = bias[bn0 + cl];
            #pragma unroll
            for (int r = 0; r < 4; ++r) {
                int rl = wm * 32 + i * 16 + q * 4 + r;
                accs[rl * 132 + cl] = acc[i * 2 + j][r] + bv;
            }
        }
    }
    __syncthreads();
    #pragma unroll
    for (int u = 0; u < 4; ++u) {
        int pair = tid + u * 512;        // 64 rows x 32 h
        int bl = pair >> 5, hl = pair & 31;
        float4 g4 = *(const float4*)&accs[bl * 132 + hl * 4];  // i,f,g,o
        int h = (bn0 >> 2) + hl, gb = bm0 + bl;
        float cold = cvec[gb * 512 + h];
        float cn = sigm(g4.y) * cold + sigm(g4.x) * tanh_f(g4.z);
        cvec[gb * 512 + h] = cn;
        _Float16 hn = (_Float16)(sigm(g4.w) * tanh_f(cn));
        h0[(size_t)gb * 1024 + h] = hn;
        if (copy) h1[(size_t)gb * 1024 + h] = hn;
    }
}

// fc2 chain, 16 samples/block, 8 waves.
DEVI void fc2_phase(char* smem, const _Float16* __restrict__ xh2,
                    const _Float16* __restrict__ Wa, const float* __restrict__ ab,
                    const _Float16* __restrict__ Wb, const float* __restrict__ bb,
                    const _Float16* __restrict__ Wc, const float* __restrict__ cb,
                    float* __restrict__ out, int b0, int t) {
    _Float16* h2s = (_Float16*)smem;       // [16][520]
    _Float16* y1s = h2s + 16 * 520;        // [16][264]
    _Float16* y2s = y1s + 16 * 264;        // [16][136]
    const int tid = threadIdx.x, wave = tid >> 6, lane = tid & 63;
    const int q = lane >> 4, m15 = lane & 15;
    #pragma unroll
    for (int c = 0; c < 2; ++c) {
        int cc = tid + c * 512, row = cc >> 6, col = (cc & 63) * 8;
        *(uint4*)&h2s[row * 520 + col] = *(const uint4*)&xh2[(size_t)(b0 + row) * 1024 + 512 + col];
    }
    __syncthreads();
    {   // y1[16,256] = lrelu(h2 @ Wa^T + ab); wave covers 32 cols
        f32x4 acc[2] = {};
        #pragma unroll 4
        for (int kk = 0; kk < 16; ++kk) {
            f16x8 af = *(const f16x8*)&h2s[m15 * 520 + kk * 32 + q * 8];
            #pragma unroll
            for (int j = 0; j < 2; ++j) {
                int n = wave * 32 + j * 16 + m15;
                f16x8 bf = *(const f16x8*)&Wa[(size_t)n * 512 + kk * 32 + q * 8];
                acc[j] = MFMA16(af, bf, acc[j]);
            }
        }
        #pragma unroll
        for (int j = 0; j < 2; ++j) {
            int col = wave * 32 + j * 16 + m15;
            float bv = ab[col];
            #pragma unroll
            for (int r = 0; r < 4; ++r)
                y1s[(q * 4 + r) * 264 + col] = (_Float16)lrelu(acc[j][r] + bv);
        }
    }
    __syncthreads();
    {   // y2[16,128] = lrelu(y1 @ Wb^T + bb); wave covers 16 cols
        f32x4 acc = {};
        #pragma unroll
        for (int kk = 0; kk < 8; ++kk) {
            f16x8 af = *(const f16x8*)&y1s[m15 * 264 + kk * 32 + q * 8];
            int n = wave * 16 + m15;
            f16x8 bf = *(const f16x8*)&Wb[(size_t)n * 256 + kk * 32 + q * 8];
            acc = MFMA16(af, bf, acc);
        }
        int col = wave * 16 + m15;
        float bv = bb[col];
        #pragma unroll
        for (int r = 0; r < 4; ++r)
            y2s[(q * 4 + r) * 136 + col] = (_Float16)lrelu(acc[r] + bv);
    }
    __syncthreads();
    if (tid < 32) {   // 16 samples x 2 outs, tanh
        int r = tid >> 1, o = tid & 1;
        float acc = cb[o];
        #pragma unroll 8
        for (int k = 0; k < 128; ++k)
            acc += (float)Wc[o * 128 + k] * (float)y2s[r * 136 + k];
        out[((size_t)(b0 + r) * TT + t) * 2 + o] = tanhf(acc);
    }
}

// ---------------------------------------------------------------- persistent decode kernel
__global__ __launch_bounds__(512) void decode_all(
        const _Float16* __restrict__ encH, const float* __restrict__ z,
        _Float16* __restrict__ eb,
        const _Float16* __restrict__ Wfc1, const float* __restrict__ biasf,
        _Float16* __restrict__ xh1,
        const _Float16* __restrict__ L1W, const float* __restrict__ L1b, float* __restrict__ c1,
        _Float16* __restrict__ xh2,
        const _Float16* __restrict__ L2W, const float* __restrict__ L2b, float* __restrict__ c2,
        const _Float16* __restrict__ C_h, const float* __restrict__ d_f,
        _Float16* __restrict__ G,
        const _Float16* __restrict__ Wa, const float* __restrict__ ab,
        const _Float16* __restrict__ Wb, const float* __restrict__ bb,
        const _Float16* __restrict__ Wc, const float* __restrict__ cb,
        float* __restrict__ out, unsigned* bar) {
    __shared__ __align__(16) char sm[62976];
    const int blk = blockIdx.x, tid = threadIdx.x;
    const int wave = tid >> 6, ln = tid & 63;

    for (int t = 0; t < TT; ++t) {
        // ================= P1: attention (4 samples/block, enc staged 1 at a time)
        {
            _Float16* encs = (_Float16*)sm;               // 25600 halves (50 KB)
            _Float16* gs   = (_Float16*)(sm + 51200);     // [4][1024]
            float* sc  = (float*)(sm + 59392);            // [4][104]
            float* wsm = (float*)(sm + 61056);            // [4][104]
            const int s0 = blk * 4;
            {   // load 4 G rows (512 uint4)
                int r = tid >> 7, c = tid & 127;
                *(uint4*)&gs[r * 1024 + c * 8] = *(const uint4*)&G[(size_t)(s0 + r) * 1024 + c * 8];
            }
            for (int sl = 0; sl < 4; ++sl) {
                const uint4* src = (const uint4*)(encH + (size_t)(s0 + sl) * (SEQ * ENC));
                uint4* dst = (uint4*)encs;
                #pragma unroll
                for (int i = 0; i < 6; ++i) dst[tid + i * 512] = src[tid + i * 512];
                if (tid < 128) dst[tid + 3072] = src[tid + 3072];
                __syncthreads();
                {   // scores: 32 groups of 16 lanes; grp -> head n, s-chunk sq
                    int grp = tid >> 4, l16 = tid & 15, n = grp & 3, sq = grp >> 2;
                    f16x8 g0 = *(const f16x8*)&gs[sl * 1024 + n * 256 + l16 * 8];
                    f16x8 g1 = *(const f16x8*)&gs[sl * 1024 + n * 256 + 128 + l16 * 8];
                    for (int it = 0; it < 13; ++it) {
                        int s = sq * 13 + it;
                        if (s < SEQ) {
                            f16x8 a0 = *(const f16x8*)&encs[s * ENC + l16 * 8];
                            f16x8 a1 = *(const f16x8*)&encs[s * ENC + 128 + l16 * 8];
                            float p = 0.f;
                            #pragma unroll
                            for (int j = 0; j < 8; ++j)
                                p += (float)a0[j] * (float)g0[j] + (float)a1[j] * (float)g1[j];
                            p += __shfl_xor(p, 1); p += __shfl_xor(p, 2);
                            p += __shfl_xor(p, 4); p += __shfl_xor(p, 8);
                            if (l16 == 0) sc[n * 104 + s] = p;
                        }
                    }
                }
                __syncthreads();
                if (wave < 4) {   // softmax, one wave per head
                    float v0 = sc[wave * 104 + ln];
                    float v1 = (ln < SEQ - 64) ? sc[wave * 104 + 64 + ln] : -1e30f;
                    float m = fmaxf(v0, v1);
                    #pragma unroll
                    for (int off = 32; off; off >>= 1) m = fmaxf(m, __shfl_xor(m, off));
                    float e0 = __expf(v0 - m);
                    float e1 = (ln < SEQ - 64) ? __expf(v1 - m) : 0.f;
                    float ss = e0 + e1;
                    #pragma unroll
                    for (int off = 32; off; off >>= 1) ss += __shfl_xor(ss, off);
                    float inv = 1.f / ss;
                    wsm[wave * 104 + ln] = e0 * inv;
                    if (ln < SEQ - 64) wsm[wave * 104 + 64 + ln] = e1 * inv;
                }
                __syncthreads();
                {   // weighted sum: wave -> (head n = wave&3, half hf); lane: 2 elems
                    int n = wave & 3, hf = wave >> 2;
                    int e0i = hf * 128 + ln * 2;
                    float a0 = 0.f, a1 = 0.f;
                    #pragma unroll 4
                    for (int s = 0; s < SEQ; ++s) {
                        float w = wsm[n * 104 + s];
                        f16x2 e2 = *(const f16x2*)&encs[s * ENC + e0i];
                        a0 += w * (float)e2.x; a1 += w * (float)e2.y;
                    }
                    f16x2 r; r.x = (_Float16)a0; r.y = (_Float16)a1;
                    *(f16x2*)&eb[(size_t)(s0 + sl) * 1088 + n * 256 + e0i] = r;
                }
                __syncthreads();
            }
            if (tid < 256) {   // z_t -> eb cols 1024..1087
                int l4 = tid >> 6, l = tid & 63;
                eb[(size_t)(s0 + l4) * 1088 + 1024 + l] =
                    (_Float16)z[((size_t)(s0 + l4) * TT + t) * LAT + l];
            }
        }
        gbar(bar);
        // ================= P2: fc1 (vtile 16x16, BM64 BN32)
        {
            f32x4 acc[1] = {};
            pgemm<64, 32, 64, 16, 16>(sm, eb, 1088, Wfc1, 1088, 1088,
                                      (blk >> 4) * 64, (blk & 15) * 32, acc);
            epi_plain<64, 32, 16, 16, 1>(acc, biasf, xh1, 1024, (blk >> 4) * 64, (blk & 15) * 32);
        }
        gbar(bar);
        // ================= P3: LSTM1 (vtile 16x16, BM64 BN128)
        {
            f32x4 acc[4] = {};
            pgemm<64, 128, 64, 32, 32>(sm, xh1, 1024, L1W, 1024, 1024,
                                       (blk >> 4) * 64, (blk & 15) * 128, acc);
            lstm_epi(sm, acc, L1b, c1, xh1 + 512, xh2, (blk >> 4) * 64, (blk & 15) * 128, true);
        }
        gbar(bar);
        // ================= P4: LSTM2
        {
            f32x4 acc[4] = {};
            pgemm<64, 128, 64, 32, 32>(sm, xh2, 1024, L2W, 1024, 1024,
                                       (blk >> 4) * 64, (blk & 15) * 128, acc);
            lstm_epi(sm, acc, L2b, c2, xh2 + 512, (_Float16*)nullptr,
                     (blk >> 4) * 64, (blk & 15) * 128, false);
        }
        gbar(bar);
        // ================= P5: q-GEMM (blocks 0..127) || fc2 chain (blocks 128..191)
        if (blk < 128) {
            f32x4 acc[4] = {};
            pgemm<64, 128, 64, 32, 32>(sm, xh2 + 512, 1024, C_h, 512, 512,
                                       (blk >> 3) * 64, (blk & 7) * 128, acc);
            epi_plain<64, 128, 32, 32, 0>(acc, d_f, G, 1024, (blk >> 3) * 64, (blk & 7) * 128);
        } else if (blk < 192) {
            fc2_phase(sm, xh2, Wa, ab, Wb, bb, Wc, cb, out, (blk - 128) * 16, t);
        }
        gbar(bar);
    }
}

// ---------------------------------------------------------------- launch
extern "C" void kernel_launch(void* const* d_in, const int* in_sizes, int n_in,
                              void* d_out, int out_size, void* d_ws, size_t ws_size,
                              hipStream_t stream) {
    const float* encoded = (const float*)d_in[0];
    const float* z       = (const float*)d_in[1];
    const float* q_w     = (const float*)d_in[2];
    const float* k_w     = (const float*)d_in[3];
    const float* v_w     = (const float*)d_in[4];
    const float* q_b     = (const float*)d_in[5];
    // d_in[6] (k_b): softmax-invariant — dropped exactly.
    const float* v_b     = (const float*)d_in[7];
    const float* out_w   = (const float*)d_in[8];
    const float* out_b   = (const float*)d_in[9];
    const float* fc1_w   = (const float*)d_in[10];
    const float* fc1_b   = (const float*)d_in[11];
    const float* l1_wih  = (const float*)d_in[12];
    const float* l1_whh  = (const float*)d_in[13];
    const float* l1_bih  = (const float*)d_in[14];
    const float* l1_bhh  = (const float*)d_in[15];
    const float* l2_wih  = (const float*)d_in[16];
    const float* l2_whh  = (const float*)d_in[17];
    const float* l2_bih  = (const float*)d_in[18];
    const float* l2_bhh  = (const float*)d_in[19];
    const float* fc2a_w  = (const float*)d_in[20];
    const float* fc2a_b  = (const float*)d_in[21];
    const float* fc2b_w  = (const float*)d_in[22];
    const float* fc2b_b  = (const float*)d_in[23];
    const float* fc2c_w  = (const float*)d_in[24];
    const float* fc2c_b  = (const float*)d_in[25];
    float* out = (float*)d_out;

    char* p = (char*)d_ws;
    auto take = [&](size_t bytes) { char* r = p; p += (bytes + 255) & ~(size_t)255; return r; };
    _Float16* encH  = (_Float16*)take(52428800);   // [1024,100,256] fp16
    _Float16* C_h   = (_Float16*)take(1048576);    // [1024,512]
    _Float16* Wfc1  = (_Float16*)take(1114112);    // [512,1088]
    _Float16* L1W   = (_Float16*)take(4194304);    // [2048,1024] rows h*4+g
    _Float16* L2W   = (_Float16*)take(4194304);
    _Float16* fc2a16= (_Float16*)take(262144);     // [256,512]
    _Float16* fc2b16= (_Float16*)take(65536);      // [128,256]
    _Float16* fc2c16= (_Float16*)take(512);        // [2,128]
    _Float16* eb    = (_Float16*)take(2228224);    // [1024,1088]
    char* zreg = p;                                // ---- zero region (10 MB + bar) ----
    _Float16* xh1 = (_Float16*)take(2097152);      // [1024,1024] = [fc1out | h1]
    _Float16* xh2 = (_Float16*)take(2097152);      // [1024,1024] = [h1 | h2]
    _Float16* G   = (_Float16*)take(2097152);      // [1024,1024]
    float* c1     = (float*)take(2097152);
    float* c2     = (float*)take(2097152);
    unsigned* bar = (unsigned*)take(256);          // ---- end zero region ----
    float* A      = (float*)take(1048576);
    float* d_f    = (float*)take(4096);
    _Float16* d_h = (_Float16*)take(2048);
    float* biasf  = (float*)take(2048);
    float* L1b    = (float*)take(8192);
    float* L2b    = (float*)take(8192);
    (void)in_sizes; (void)n_in; (void)out_size; (void)ws_size;

    zero_ws<<<2561, 256, 0, stream>>>((uint4*)zreg);
    conv_enc<<<25600, 256, 0, stream>>>((const float4*)encoded, (f16x4*)encH);
    prep_qk<<<1024, 256, 0, stream>>>(k_w, q_w, q_b, C_h, d_f, d_h);
    prep_A<<<512, 256, 0, stream>>>(fc1_w, out_w, A);
    prep_wfc1<<<512, 256, 0, stream>>>(A, v_w, v_b, fc1_w, out_b, fc1_b, Wfc1, biasf);
    prep_lstm<<<8192, 256, 0, stream>>>(l1_wih, l1_whh, l1_bih, l1_bhh, L1W, L1b);
    prep_lstm<<<8192, 256, 0, stream>>>(l2_wih, l2_whh, l2_bih, l2_bhh, L2W, L2b);
    prep_fc2c<<<641, 256, 0, stream>>>(fc2a_w, fc2b_w, fc2c_w, fc2a16, fc2b16, fc2c16);
    bcast_G<<<1024, 256, 0, stream>>>(d_h, G);

    decode_all<<<256, 512, 0, stream>>>(encH, z, eb, Wfc1, biasf,
                                        xh1, L1W, L1b, c1,
                                        xh2, L2W, L2b, c2,
                                        C_h, d_f, G,
                                        fc2a16, fc2a_b, fc2b16, fc2b_b, fc2c16, fc2c_b,
                                        out, bar);
}

// Round 6
// 7303.058 us; speedup vs baseline: 1.1621x; 1.1621x over previous
//
#include <hip/hip_runtime.h>

// Generator_78683800862785: attention+LSTM decoder, BS=1024, T=30.
// R5b: persistent kernel (256 blocks = 1/CU) with fixed grid barrier
// (relaxed spin + constant s_sleep + single acquire fence) and
// register-prefetch pipelined attention staging. fp16 MFMA, fp32 accum;
// K/V folded into C = scale*K_w^T Q_w; att->out->fc1 folded into Wfc1;
// LSTM gate-ew fused after GEMM (weight rows h*4+gate).

#define DEVI __device__ __forceinline__

typedef _Float16 f16x8 __attribute__((ext_vector_type(8)));
typedef _Float16 f16x4 __attribute__((ext_vector_type(4)));
typedef _Float16 f16x2 __attribute__((ext_vector_type(2)));
typedef float    f32x4 __attribute__((ext_vector_type(4)));

#define BSZ 1024
#define SEQ 100
#define ENC 256
#define LAT 64
#define TT  30

#define MFMA16(a, b, c) __builtin_amdgcn_mfma_f32_16x16x32_f16(a, b, c, 0, 0, 0)

DEVI float lrelu(float v) { return v >= 0.f ? v : 0.2f * v; }
DEVI float sigm(float x)  { return 1.f / (1.f + __expf(-x)); }
DEVI float tanh_f(float x){ return 1.f - 2.f / (1.f + __expf(2.f * x)); }

// ---------------------------------------------------------------- setup kernels
__global__ __launch_bounds__(256) void zero_ws(uint4* __restrict__ p) {
    uint4 z; z.x = z.y = z.z = z.w = 0u;
    p[(size_t)blockIdx.x * 256 + threadIdx.x] = z;
}

__global__ __launch_bounds__(256) void conv_enc(const float4* __restrict__ src,
                                                f16x4* __restrict__ dst) {
    size_t i = (size_t)blockIdx.x * 256 + threadIdx.x;
    float4 v = src[i];
    f16x4 h;
    h.x = (_Float16)v.x; h.y = (_Float16)v.y; h.z = (_Float16)v.z; h.w = (_Float16)v.w;
    dst[i] = h;
}

// C[ne,h] = scale * sum_d k_w[n*128+d, e] * q_w[n*128+d, h]   (fp16 out)
// d[ne]   = scale * sum_d k_w[n*128+d, e] * q_b[n*128+d]
__global__ __launch_bounds__(256) void prep_qk(const float* __restrict__ k_w,
                                               const float* __restrict__ q_w,
                                               const float* __restrict__ q_b,
                                               _Float16* __restrict__ C_h,
                                               float* __restrict__ d_f,
                                               _Float16* __restrict__ d_h) {
    const int ne = blockIdx.x, n = ne >> 8, e = ne & 255, tid = threadIdx.x;
    const float scale = 0.08838834764831845f;  // 1/sqrt(128)
    float a0 = 0.f, a1 = 0.f;
    for (int dd = 0; dd < 128; ++dd) {
        float kv = k_w[(n * 128 + dd) * 256 + e];
        a0 += kv * q_w[(n * 128 + dd) * 512 + tid];
        a1 += kv * q_w[(n * 128 + dd) * 512 + 256 + tid];
    }
    C_h[(size_t)ne * 512 + tid]       = (_Float16)(scale * a0);
    C_h[(size_t)ne * 512 + 256 + tid] = (_Float16)(scale * a1);
    float pq = (tid < 128) ? k_w[(n * 128 + tid) * 256 + e] * q_b[n * 128 + tid] : 0.f;
    #pragma unroll
    for (int off = 32; off; off >>= 1) pq += __shfl_down(pq, off);
    __shared__ float red[4];
    if ((tid & 63) == 0) red[tid >> 6] = pq;
    __syncthreads();
    if (tid == 0) {
        float s = scale * (red[0] + red[1] + red[2] + red[3]);
        d_f[ne] = s; d_h[ne] = (_Float16)s;
    }
}

// A[h,k] = sum_m fc1_w[h, m] * out_w[m, k]
__global__ __launch_bounds__(256) void prep_A(const float* __restrict__ fc1_w,
                                              const float* __restrict__ out_w,
                                              float* __restrict__ A) {
    const int h = blockIdx.x, tid = threadIdx.x;
    float a0 = 0.f, a1 = 0.f;
    for (int m = 0; m < 512; ++m) {
        float fv = fc1_w[h * 576 + m];
        a0 += fv * out_w[m * 512 + tid];
        a1 += fv * out_w[m * 512 + 256 + tid];
    }
    A[(size_t)h * 512 + tid]       = a0;
    A[(size_t)h * 512 + 256 + tid] = a1;
}

// Wfc1[h, n*256+e] = sum_d A[h, n*128+d]*v_w[n*128+d, e]; cols 1024..1087 = fc1_w[h,512+l]
__global__ __launch_bounds__(256) void prep_wfc1(const float* __restrict__ A,
                                                 const float* __restrict__ v_w,
                                                 const float* __restrict__ v_b,
                                                 const float* __restrict__ fc1_w,
                                                 const float* __restrict__ out_b,
                                                 const float* __restrict__ fc1_b,
                                                 _Float16* __restrict__ Wfc1,
                                                 float* __restrict__ biasf) {
    const int h = blockIdx.x, tid = threadIdx.x;
    #pragma unroll
    for (int g = 0; g < 4; ++g) {
        float acc = 0.f;
        for (int dd = 0; dd < 128; ++dd)
            acc += A[h * 512 + g * 128 + dd] * v_w[(g * 128 + dd) * 256 + tid];
        Wfc1[(size_t)h * 1088 + g * 256 + tid] = (_Float16)acc;
    }
    if (tid < 64)
        Wfc1[(size_t)h * 1088 + 1024 + tid] = (_Float16)fc1_w[h * 576 + 512 + tid];
    float ps = A[h * 512 + tid] * v_b[tid] + A[h * 512 + 256 + tid] * v_b[256 + tid]
             + fc1_w[h * 576 + tid] * out_b[tid] + fc1_w[h * 576 + 256 + tid] * out_b[256 + tid];
    #pragma unroll
    for (int off = 32; off; off >>= 1) ps += __shfl_down(ps, off);
    __shared__ float red[4];
    if ((tid & 63) == 0) red[tid >> 6] = ps;
    __syncthreads();
    if (tid == 0) biasf[h] = red[0] + red[1] + red[2] + red[3] + fc1_b[h];
}

// LSTM weights: concat [wih|whh] -> fp16 [2048 x 1024], rows reordered to h*4+gate.
__global__ __launch_bounds__(256) void prep_lstm(const float* __restrict__ wih,
                                                 const float* __restrict__ whh,
                                                 const float* __restrict__ bih,
                                                 const float* __restrict__ bhh,
                                                 _Float16* __restrict__ Wc,
                                                 float* __restrict__ bc) {
    int idx = blockIdx.x * 256 + threadIdx.x;  // 2,097,152
    int rp = idx >> 10, cc = idx & 1023;
    int h = rp >> 2, g = rp & 3;
    int rsrc = g * 512 + h;
    float v = (cc < 512) ? wih[(size_t)rsrc * 512 + cc] : whh[(size_t)rsrc * 512 + cc - 512];
    Wc[idx] = (_Float16)v;
    if (idx < 2048) {
        int h2 = idx >> 2, g2 = idx & 3;
        bc[idx] = bih[g2 * 512 + h2] + bhh[g2 * 512 + h2];
    }
}

// fc2 weights -> fp16 casts (GEMMs run X @ W^T, so no transpose needed).
__global__ __launch_bounds__(256) void prep_fc2c(const float* __restrict__ aw,
                                                 const float* __restrict__ bw,
                                                 const float* __restrict__ cw,
                                                 _Float16* __restrict__ a16,
                                                 _Float16* __restrict__ b16,
                                                 _Float16* __restrict__ c16) {
    int i = blockIdx.x * 256 + threadIdx.x;
    if (i < 131072) a16[i] = (_Float16)aw[i];
    else if (i < 163840) b16[i - 131072] = (_Float16)bw[i - 131072];
    else if (i < 164096) c16[i - 163840] = (_Float16)cw[i - 163840];
}

__global__ __launch_bounds__(256) void bcast_G(const _Float16* __restrict__ d_h,
                                               _Float16* __restrict__ G) {
    const int b = blockIdx.x, tid = threadIdx.x;
    f16x4 v = *(const f16x4*)(d_h + tid * 4);
    *(f16x4*)(G + (size_t)b * 1024 + tid * 4) = v;
}

// ---------------------------------------------------------------- grid barrier
// Sense-reversing; counter at bar[0], sense at bar[32] (separate cachelines).
// Spin is RELAXED (no per-poll invalidate) + constant s_sleep; single acquire
// fence at exit. All 256 blocks co-resident (1/CU).
DEVI void gbar(unsigned* bar) {
    __syncthreads();
    if (threadIdx.x == 0) {
        unsigned g = __hip_atomic_load(bar + 32, __ATOMIC_RELAXED, __HIP_MEMORY_SCOPE_AGENT);
        unsigned a = __hip_atomic_fetch_add(bar, 1u, __ATOMIC_RELEASE, __HIP_MEMORY_SCOPE_AGENT);
        if (a == 255u) {
            __hip_atomic_store(bar, 0u, __ATOMIC_RELAXED, __HIP_MEMORY_SCOPE_AGENT);
            __hip_atomic_store(bar + 32, g + 1u, __ATOMIC_RELEASE, __HIP_MEMORY_SCOPE_AGENT);
        } else {
            while (__hip_atomic_load(bar + 32, __ATOMIC_RELAXED, __HIP_MEMORY_SCOPE_AGENT) == g)
                __builtin_amdgcn_s_sleep(4);
        }
    }
    __syncthreads();
    __builtin_amdgcn_fence(__ATOMIC_ACQUIRE, "agent");
}

// ---------------------------------------------------------------- GEMM core (512 thr, reg-db)
// out = X @ W^T on BMxBN tile; W row-major [N,K]. acc: row=(lane>>4)*4+r, col=lane&15.
template <int BM, int BN, int BK, int WM, int WN>
DEVI void pgemm(char* smem_raw, const _Float16* __restrict__ X, int ldx,
                const _Float16* __restrict__ W, int ldw, int K,
                int bm0, int bn0, f32x4* acc) {
    constexpr int LDT = BK + 8;
    _Float16* Xs = (_Float16*)smem_raw;
    _Float16* Ws = Xs + BM * LDT;
    const int tid = threadIdx.x, wave = tid >> 6, lane = tid & 63;
    constexpr int WROWS = BM / WM;
    const int wm = wave % WROWS, wn = wave / WROWS;
    constexpr int MT = WM / 16, NT = WN / 16;
    const int q = lane >> 4, m15 = lane & 15;
    constexpr int CPR = BK / 8;
    constexpr int XCH = BM * CPR, WCH = BN * CPR;
    constexpr int XPT = (XCH + 511) / 512, WPT = (WCH + 511) / 512;
    uint4 xr[XPT], wr[WPT];
    auto ldregs = [&](int k0) {
        #pragma unroll
        for (int c = 0; c < XPT; ++c) {
            int cc = tid + c * 512;
            if ((XCH % 512 == 0) || cc < XCH) {
                int row = cc / CPR, col = (cc % CPR) * 8;
                xr[c] = *(const uint4*)&X[(size_t)(bm0 + row) * ldx + k0 + col];
            }
        }
        #pragma unroll
        for (int c = 0; c < WPT; ++c) {
            int cc = tid + c * 512;
            if ((WCH % 512 == 0) || cc < WCH) {
                int row = cc / CPR, col = (cc % CPR) * 8;
                wr[c] = *(const uint4*)&W[(size_t)(bn0 + row) * ldw + k0 + col];
            }
        }
    };
    ldregs(0);
    for (int k0 = 0; k0 < K; k0 += BK) {
        #pragma unroll
        for (int c = 0; c < XPT; ++c) {
            int cc = tid + c * 512;
            if ((XCH % 512 == 0) || cc < XCH) {
                int row = cc / CPR, col = (cc % CPR) * 8;
                *(uint4*)&Xs[row * LDT + col] = xr[c];
            }
        }
        #pragma unroll
        for (int c = 0; c < WPT; ++c) {
            int cc = tid + c * 512;
            if ((WCH % 512 == 0) || cc < WCH) {
                int row = cc / CPR, col = (cc % CPR) * 8;
                *(uint4*)&Ws[row * LDT + col] = wr[c];
            }
        }
        __syncthreads();
        if (k0 + BK < K) ldregs(k0 + BK);   // overlap next-tile loads with MFMA
        #pragma unroll
        for (int kk = 0; kk < BK / 32; ++kk) {
            f16x8 af[MT], bf[NT];
            #pragma unroll
            for (int i = 0; i < MT; ++i)
                af[i] = *(const f16x8*)&Xs[(wm * WM + i * 16 + m15) * LDT + kk * 32 + q * 8];
            #pragma unroll
            for (int j = 0; j < NT; ++j)
                bf[j] = *(const f16x8*)&Ws[(wn * WN + j * 16 + m15) * LDT + kk * 32 + q * 8];
            #pragma unroll
            for (int i = 0; i < MT; ++i)
                #pragma unroll
                for (int j = 0; j < NT; ++j)
                    acc[i * NT + j] = MFMA16(af[i], bf[j], acc[i * NT + j]);
        }
        __syncthreads();
    }
}

template <int BM, int BN, int WM, int WN, int ACT>
DEVI void epi_plain(const f32x4* acc, const float* __restrict__ bias,
                    _Float16* __restrict__ out, int ldo, int bm0, int bn0) {
    const int tid = threadIdx.x, wave = tid >> 6, lane = tid & 63;
    constexpr int WROWS = BM / WM;
    const int wm = wave % WROWS, wn = wave / WROWS;
    constexpr int MT = WM / 16, NT = WN / 16;
    const int q = lane >> 4, m15 = lane & 15;
    #pragma unroll
    for (int i = 0; i < MT; ++i) {
        #pragma unroll
        for (int j = 0; j < NT; ++j) {
            int col = bn0 + wn * WN + j * 16 + m15;
            float bv = bias[col];
            #pragma unroll
            for (int r = 0; r < 4; ++r) {
                int rowg = bm0 + wm * WM + i * 16 + q * 4 + r;
                float v = acc[i * NT + j][r] + bv;
                if (ACT == 1) v = lrelu(v);
                out[(size_t)rowg * ldo + col] = (_Float16)v;
            }
        }
    }
}

// LSTM epilogue: bias + gate math fused; weight rows h*4+gate so each 128-col
// tile owns 32 h x 4 gates. acc from pgemm<64,128,64,32,32>.
DEVI void lstm_epi(char* smem, const f32x4* acc, const float* __restrict__ bias,
                   float* __restrict__ cvec, _Float16* __restrict__ h0,
                   _Float16* __restrict__ h1, int bm0, int bn0, bool copy) {
    float* accs = (float*)smem;  // [64][132]
    const int tid = threadIdx.x, wave = tid >> 6, lane = tid & 63;
    const int wm = wave & 1, wn = wave >> 1, q = lane >> 4, m15 = lane & 15;
    #pragma unroll
    for (int i = 0; i < 2; ++i) {
        #pragma unroll
        for (int j = 0; j < 2; ++j) {
            int cl = wn * 32 + j * 16 + m15;
            float bv = bias[bn0 + cl];
            #pragma unroll
            for (int r = 0; r < 4; ++r) {
                int rl = wm * 32 + i * 16 + q * 4 + r;
                accs[rl * 132 + cl] = acc[i * 2 + j][r] + bv;
            }
        }
    }
    __syncthreads();
    #pragma unroll
    for (int u = 0; u < 4; ++u) {
        int pair = tid + u * 512;        // 64 rows x 32 h
        int bl = pair >> 5, hl = pair & 31;
        float4 g4 = *(const float4*)&accs[bl * 132 + hl * 4];  // i,f,g,o
        int h = (bn0 >> 2) + hl, gb = bm0 + bl;
        float cold = cvec[gb * 512 + h];
        float cn = sigm(g4.y) * cold + sigm(g4.x) * tanh_f(g4.z);
        cvec[gb * 512 + h] = cn;
        _Float16 hn = (_Float16)(sigm(g4.w) * tanh_f(cn));
        h0[(size_t)gb * 1024 + h] = hn;
        if (copy) h1[(size_t)gb * 1024 + h] = hn;
    }
}

// fc2 chain, 16 samples/block, 8 waves.
DEVI void fc2_phase(char* smem, const _Float16* __restrict__ xh2,
                    const _Float16* __restrict__ Wa, const float* __restrict__ ab,
                    const _Float16* __restrict__ Wb, const float* __restrict__ bb,
                    const _Float16* __restrict__ Wc, const float* __restrict__ cb,
                    float* __restrict__ out, int b0, int t) {
    _Float16* h2s = (_Float16*)smem;       // [16][520]
    _Float16* y1s = h2s + 16 * 520;        // [16][264]
    _Float16* y2s = y1s + 16 * 264;        // [16][136]
    const int tid = threadIdx.x, wave = tid >> 6, lane = tid & 63;
    const int q = lane >> 4, m15 = lane & 15;
    #pragma unroll
    for (int c = 0; c < 2; ++c) {
        int cc = tid + c * 512, row = cc >> 6, col = (cc & 63) * 8;
        *(uint4*)&h2s[row * 520 + col] = *(const uint4*)&xh2[(size_t)(b0 + row) * 1024 + 512 + col];
    }
    __syncthreads();
    {   // y1[16,256] = lrelu(h2 @ Wa^T + ab); wave covers 32 cols
        f32x4 acc[2] = {};
        #pragma unroll 4
        for (int kk = 0; kk < 16; ++kk) {
            f16x8 af = *(const f16x8*)&h2s[m15 * 520 + kk * 32 + q * 8];
            #pragma unroll
            for (int j = 0; j < 2; ++j) {
                int n = wave * 32 + j * 16 + m15;
                f16x8 bf = *(const f16x8*)&Wa[(size_t)n * 512 + kk * 32 + q * 8];
                acc[j] = MFMA16(af, bf, acc[j]);
            }
        }
        #pragma unroll
        for (int j = 0; j < 2; ++j) {
            int col = wave * 32 + j * 16 + m15;
            float bv = ab[col];
            #pragma unroll
            for (int r = 0; r < 4; ++r)
                y1s[(q * 4 + r) * 264 + col] = (_Float16)lrelu(acc[j][r] + bv);
        }
    }
    __syncthreads();
    {   // y2[16,128] = lrelu(y1 @ Wb^T + bb); wave covers 16 cols
        f32x4 acc = {};
        #pragma unroll
        for (int kk = 0; kk < 8; ++kk) {
            f16x8 af = *(const f16x8*)&y1s[m15 * 264 + kk * 32 + q * 8];
            int n = wave * 16 + m15;
            f16x8 bf = *(const f16x8*)&Wb[(size_t)n * 256 + kk * 32 + q * 8];
            acc = MFMA16(af, bf, acc);
        }
        int col = wave * 16 + m15;
        float bv = bb[col];
        #pragma unroll
        for (int r = 0; r < 4; ++r)
            y2s[(q * 4 + r) * 136 + col] = (_Float16)lrelu(acc[r] + bv);
    }
    __syncthreads();
    if (tid < 32) {   // 16 samples x 2 outs, tanh
        int r = tid >> 1, o = tid & 1;
        float acc = cb[o];
        #pragma unroll 8
        for (int k = 0; k < 128; ++k)
            acc += (float)Wc[o * 128 + k] * (float)y2s[r * 136 + k];
        out[((size_t)(b0 + r) * TT + t) * 2 + o] = tanhf(acc);
    }
}

// ---------------------------------------------------------------- persistent decode kernel
__global__ __launch_bounds__(512) void decode_all(
        const _Float16* __restrict__ encH, const float* __restrict__ z,
        _Float16* __restrict__ eb,
        const _Float16* __restrict__ Wfc1, const float* __restrict__ biasf,
        _Float16* __restrict__ xh1,
        const _Float16* __restrict__ L1W, const float* __restrict__ L1b, float* __restrict__ c1,
        _Float16* __restrict__ xh2,
        const _Float16* __restrict__ L2W, const float* __restrict__ L2b, float* __restrict__ c2,
        const _Float16* __restrict__ C_h, const float* __restrict__ d_f,
        _Float16* __restrict__ G,
        const _Float16* __restrict__ Wa, const float* __restrict__ ab,
        const _Float16* __restrict__ Wb, const float* __restrict__ bb,
        const _Float16* __restrict__ Wc, const float* __restrict__ cb,
        float* __restrict__ out, unsigned* bar) {
    __shared__ __align__(16) char sm[62976];
    const int blk = blockIdx.x, tid = threadIdx.x;
    const int wave = tid >> 6, ln = tid & 63;

    for (int t = 0; t < TT; ++t) {
        // ================= P1: attention (4 samples/block, reg-prefetch pipeline)
        {
            _Float16* encs = (_Float16*)sm;               // 25600 halves (50 KB)
            _Float16* gs   = (_Float16*)(sm + 51200);     // [4][1024]
            float* sc  = (float*)(sm + 59392);            // [4][104]
            float* wsm = (float*)(sm + 61056);            // [4][104]
            const int s0 = blk * 4;
            uint4 pre[7];
            auto ldenc = [&](int sl) {   // issue sample sl's 50 KB into regs
                const uint4* src = (const uint4*)(encH + (size_t)(s0 + sl) * (SEQ * ENC));
                #pragma unroll
                for (int i = 0; i < 6; ++i) pre[i] = src[tid + i * 512];
                if (tid < 128) pre[6] = src[tid + 3072];
            };
            {   // load 4 G rows (512 uint4)
                int r = tid >> 7, c = tid & 127;
                *(uint4*)&gs[r * 1024 + c * 8] = *(const uint4*)&G[(size_t)(s0 + r) * 1024 + c * 8];
            }
            ldenc(0);
            for (int sl = 0; sl < 4; ++sl) {
                {   // regs -> LDS
                    uint4* dst = (uint4*)encs;
                    #pragma unroll
                    for (int i = 0; i < 6; ++i) dst[tid + i * 512] = pre[i];
                    if (tid < 128) dst[tid + 3072] = pre[6];
                }
                __syncthreads();
                if (sl < 3) ldenc(sl + 1);   // next sample's loads fly during compute
                {   // scores: 32 groups of 16 lanes; grp -> head n, s-chunk sq
                    int grp = tid >> 4, l16 = tid & 15, n = grp & 3, sq = grp >> 2;
                    f16x8 g0 = *(const f16x8*)&gs[sl * 1024 + n * 256 + l16 * 8];
                    f16x8 g1 = *(const f16x8*)&gs[sl * 1024 + n * 256 + 128 + l16 * 8];
                    for (int it = 0; it < 13; ++it) {
                        int s = sq * 13 + it;
                        if (s < SEQ) {
                            f16x8 a0 = *(const f16x8*)&encs[s * ENC + l16 * 8];
                            f16x8 a1 = *(const f16x8*)&encs[s * ENC + 128 + l16 * 8];
                            float p = 0.f;
                            #pragma unroll
                            for (int j = 0; j < 8; ++j)
                                p += (float)a0[j] * (float)g0[j] + (float)a1[j] * (float)g1[j];
                            p += __shfl_xor(p, 1); p += __shfl_xor(p, 2);
                            p += __shfl_xor(p, 4); p += __shfl_xor(p, 8);
                            if (l16 == 0) sc[n * 104 + s] = p;
                        }
                    }
                }
                __syncthreads();
                if (wave < 4) {   // softmax, one wave per head
                    float v0 = sc[wave * 104 + ln];
                    float v1 = (ln < SEQ - 64) ? sc[wave * 104 + 64 + ln] : -1e30f;
                    float m = fmaxf(v0, v1);
                    #pragma unroll
                    for (int off = 32; off; off >>= 1) m = fmaxf(m, __shfl_xor(m, off));
                    float e0 = __expf(v0 - m);
                    float e1 = (ln < SEQ - 64) ? __expf(v1 - m) : 0.f;
                    float ss = e0 + e1;
                    #pragma unroll
                    for (int off = 32; off; off >>= 1) ss += __shfl_xor(ss, off);
                    float inv = 1.f / ss;
                    wsm[wave * 104 + ln] = e0 * inv;
                    if (ln < SEQ - 64) wsm[wave * 104 + 64 + ln] = e1 * inv;
                }
                __syncthreads();
                {   // weighted sum: wave -> (head n = wave&3, half hf); lane: 2 elems
                    int n = wave & 3, hf = wave >> 2;
                    int e0i = hf * 128 + ln * 2;
                    float a0 = 0.f, a1 = 0.f;
                    #pragma unroll 4
                    for (int s = 0; s < SEQ; ++s) {
                        float w = wsm[n * 104 + s];
                        f16x2 e2 = *(const f16x2*)&encs[s * ENC + e0i];
                        a0 += w * (float)e2.x; a1 += w * (float)e2.y;
                    }
                    f16x2 r; r.x = (_Float16)a0; r.y = (_Float16)a1;
                    *(f16x2*)&eb[(size_t)(s0 + sl) * 1088 + n * 256 + e0i] = r;
                }
                __syncthreads();
            }
            if (tid < 256) {   // z_t -> eb cols 1024..1087
                int l4 = tid >> 6, l = tid & 63;
                eb[(size_t)(s0 + l4) * 1088 + 1024 + l] =
                    (_Float16)z[((size_t)(s0 + l4) * TT + t) * LAT + l];
            }
        }
        gbar(bar);
        // ================= P2: fc1 (vtile 16x16, BM64 BN32)
        {
            f32x4 acc[1] = {};
            pgemm<64, 32, 64, 16, 16>(sm, eb, 1088, Wfc1, 1088, 1088,
                                      (blk >> 4) * 64, (blk & 15) * 32, acc);
            epi_plain<64, 32, 16, 16, 1>(acc, biasf, xh1, 1024, (blk >> 4) * 64, (blk & 15) * 32);
        }
        gbar(bar);
        // ================= P3: LSTM1 (vtile 16x16, BM64 BN128)
        {
            f32x4 acc[4] = {};
            pgemm<64, 128, 64, 32, 32>(sm, xh1, 1024, L1W, 1024, 1024,
                                       (blk >> 4) * 64, (blk & 15) * 128, acc);
            lstm_epi(sm, acc, L1b, c1, xh1 + 512, xh2, (blk >> 4) * 64, (blk & 15) * 128, true);
        }
        gbar(bar);
        // ================= P4: LSTM2
        {
            f32x4 acc[4] = {};
            pgemm<64, 128, 64, 32, 32>(sm, xh2, 1024, L2W, 1024, 1024,
                                       (blk >> 4) * 64, (blk & 15) * 128, acc);
            lstm_epi(sm, acc, L2b, c2, xh2 + 512, (_Float16*)nullptr,
                     (blk >> 4) * 64, (blk & 15) * 128, false);
        }
        gbar(bar);
        // ================= P5: q-GEMM (blocks 0..127) || fc2 chain (blocks 128..191)
        if (blk < 128) {
            f32x4 acc[4] = {};
            pgemm<64, 128, 64, 32, 32>(sm, xh2 + 512, 1024, C_h, 512, 512,
                                       (blk >> 3) * 64, (blk & 7) * 128, acc);
            epi_plain<64, 128, 32, 32, 0>(acc, d_f, G, 1024, (blk >> 3) * 64, (blk & 7) * 128);
        } else if (blk < 192) {
            fc2_phase(sm, xh2, Wa, ab, Wb, bb, Wc, cb, out, (blk - 128) * 16, t);
        }
        gbar(bar);
    }
}

// ---------------------------------------------------------------- launch
extern "C" void kernel_launch(void* const* d_in, const int* in_sizes, int n_in,
                              void* d_out, int out_size, void* d_ws, size_t ws_size,
                              hipStream_t stream) {
    const float* encoded = (const float*)d_in[0];
    const float* z       = (const float*)d_in[1];
    const float* q_w     = (const float*)d_in[2];
    const float* k_w     = (const float*)d_in[3];
    const float* v_w     = (const float*)d_in[4];
    const float* q_b     = (const float*)d_in[5];
    // d_in[6] (k_b): softmax-invariant — dropped exactly.
    const float* v_b     = (const float*)d_in[7];
    const float* out_w   = (const float*)d_in[8];
    const float* out_b   = (const float*)d_in[9];
    const float* fc1_w   = (const float*)d_in[10];
    const float* fc1_b   = (const float*)d_in[11];
    const float* l1_wih  = (const float*)d_in[12];
    const float* l1_whh  = (const float*)d_in[13];
    const float* l1_bih  = (const float*)d_in[14];
    const float* l1_bhh  = (const float*)d_in[15];
    const float* l2_wih  = (const float*)d_in[16];
    const float* l2_whh  = (const float*)d_in[17];
    const float* l2_bih  = (const float*)d_in[18];
    const float* l2_bhh  = (const float*)d_in[19];
    const float* fc2a_w  = (const float*)d_in[20];
    const float* fc2a_b  = (const float*)d_in[21];
    const float* fc2b_w  = (const float*)d_in[22];
    const float* fc2b_b  = (const float*)d_in[23];
    const float* fc2c_w  = (const float*)d_in[24];
    const float* fc2c_b  = (const float*)d_in[25];
    float* out = (float*)d_out;

    char* p = (char*)d_ws;
    auto take = [&](size_t bytes) { char* r = p; p += (bytes + 255) & ~(size_t)255; return r; };
    _Float16* encH  = (_Float16*)take(52428800);   // [1024,100,256] fp16
    _Float16* C_h   = (_Float16*)take(1048576);    // [1024,512]
    _Float16* Wfc1  = (_Float16*)take(1114112);    // [512,1088]
    _Float16* L1W   = (_Float16*)take(4194304);    // [2048,1024] rows h*4+g
    _Float16* L2W   = (_Float16*)take(4194304);
    _Float16* fc2a16= (_Float16*)take(262144);     // [256,512]
    _Float16* fc2b16= (_Float16*)take(65536);      // [128,256]
    _Float16* fc2c16= (_Float16*)take(512);        // [2,128]
    _Float16* eb    = (_Float16*)take(2228224);    // [1024,1088]
    char* zreg = p;                                // ---- zero region (10 MB + bar) ----
    _Float16* xh1 = (_Float16*)take(2097152);      // [1024,1024] = [fc1out | h1]
    _Float16* xh2 = (_Float16*)take(2097152);      // [1024,1024] = [h1 | h2]
    _Float16* G   = (_Float16*)take(2097152);      // [1024,1024]
    float* c1     = (float*)take(2097152);
    float* c2     = (float*)take(2097152);
    unsigned* bar = (unsigned*)take(256);          // ---- end zero region ----
    float* A      = (float*)take(1048576);
    float* d_f    = (float*)take(4096);
    _Float16* d_h = (_Float16*)take(2048);
    float* biasf  = (float*)take(2048);
    float* L1b    = (float*)take(8192);
    float* L2b    = (float*)take(8192);
    (void)in_sizes; (void)n_in; (void)out_size; (void)ws_size;

    zero_ws<<<2561, 256, 0, stream>>>((uint4*)zreg);
    conv_enc<<<25600, 256, 0, stream>>>((const float4*)encoded, (f16x4*)encH);
    prep_qk<<<1024, 256, 0, stream>>>(k_w, q_w, q_b, C_h, d_f, d_h);
    prep_A<<<512, 256, 0, stream>>>(fc1_w, out_w, A);
    prep_wfc1<<<512, 256, 0, stream>>>(A, v_w, v_b, fc1_w, out_b, fc1_b, Wfc1, biasf);
    prep_lstm<<<8192, 256, 0, stream>>>(l1_wih, l1_whh, l1_bih, l1_bhh, L1W, L1b);
    prep_lstm<<<8192, 256, 0, stream>>>(l2_wih, l2_whh, l2_bih, l2_bhh, L2W, L2b);
    prep_fc2c<<<641, 256, 0, stream>>>(fc2a_w, fc2b_w, fc2c_w, fc2a16, fc2b16, fc2c16);
    bcast_G<<<1024, 256, 0, stream>>>(d_h, G);

    decode_all<<<256, 512, 0, stream>>>(encH, z, eb, Wfc1, biasf,
                                        xh1, L1W, L1b, c1,
                                        xh2, L2W, L2b, c2,
                                        C_h, d_f, G,
                                        fc2a16, fc2a_b, fc2b16, fc2b_b, fc2c16, fc2c_b,
                                        out, bar);
}